// Round 16
// baseline (280.405 us; speedup 1.0000x reference)
//
#include <hip/hip_runtime.h>

#define S_LEN  2048
#define HIDDEN 512
#define NHEAD  8
#define DHEAD  64
#define NSEL   256
#define ROWS_A 8
#define SCALE_ 0.125f

// intra-wave LDS producer->consumer sync (lockstep lanes + drain LDS queue)
#define WAVE_SYNC() __asm__ volatile("s_waitcnt lgkmcnt(0)" ::: "memory")

// monotone float->uint mapping (ascending float == ascending uint)
__device__ __forceinline__ unsigned mapu(float f) {
  unsigned u = __float_as_uint(f);
  return (u & 0x80000000u) ? ~u : (u | 0x80000000u);
}
// inverse of mapu
__device__ __forceinline__ float unmapu(unsigned x) {
  return __uint_as_float((x & 0x80000000u) ? (x & 0x7FFFFFFFu) : ~x);
}

union H4 { _Float16 h[4]; uint2 u2; };   // 4 packed fp16 <-> 8B

// ---- VALIDATED 256-thread GEMM body (r10-r15): 64x64 tile, 4x4 micro,
// double-buffered register staging.
__device__ __forceinline__ void gemm_nt_body(const float* __restrict__ A,
                                             const float* __restrict__ B,
                                             float* __restrict__ C,
                                             int K, int N, int m0, int n0,
                                             float (*As)[68], float (*Bs)[68]) {
  const int t  = threadIdx.x;
  const int tx = t & 15, ty = t >> 4;
  const int rr = t >> 3, cc = (t & 7) << 2;
  float acc[4][4] = {};

  float4 fa0 = *(const float4*)&A[(size_t)(m0 + rr)      * K + cc];
  float4 fa1 = *(const float4*)&A[(size_t)(m0 + rr + 32) * K + cc];
  float4 fb0 = *(const float4*)&B[(size_t)(n0 + rr)      * K + cc];
  float4 fb1 = *(const float4*)&B[(size_t)(n0 + rr + 32) * K + cc];

  for (int k0 = 0; k0 < K; k0 += 32) {
    __syncthreads();
    As[cc + 0][rr] = fa0.x; As[cc + 1][rr] = fa0.y; As[cc + 2][rr] = fa0.z; As[cc + 3][rr] = fa0.w;
    As[cc + 0][rr + 32] = fa1.x; As[cc + 1][rr + 32] = fa1.y; As[cc + 2][rr + 32] = fa1.z; As[cc + 3][rr + 32] = fa1.w;
    Bs[cc + 0][rr] = fb0.x; Bs[cc + 1][rr] = fb0.y; Bs[cc + 2][rr] = fb0.z; Bs[cc + 3][rr] = fb0.w;
    Bs[cc + 0][rr + 32] = fb1.x; Bs[cc + 1][rr + 32] = fb1.y; Bs[cc + 2][rr + 32] = fb1.z; Bs[cc + 3][rr + 32] = fb1.w;
    __syncthreads();
    if (k0 + 32 < K) {
      fa0 = *(const float4*)&A[(size_t)(m0 + rr)      * K + k0 + 32 + cc];
      fa1 = *(const float4*)&A[(size_t)(m0 + rr + 32) * K + k0 + 32 + cc];
      fb0 = *(const float4*)&B[(size_t)(n0 + rr)      * K + k0 + 32 + cc];
      fb1 = *(const float4*)&B[(size_t)(n0 + rr + 32) * K + k0 + 32 + cc];
    }
#pragma unroll
    for (int kk = 0; kk < 32; ++kk) {
      const float4 a4 = *(const float4*)&As[kk][ty * 4];
      const float4 b4 = *(const float4*)&Bs[kk][tx * 4];
      const float a[4] = {a4.x, a4.y, a4.z, a4.w};
      const float b[4] = {b4.x, b4.y, b4.z, b4.w};
#pragma unroll
      for (int i = 0; i < 4; ++i)
#pragma unroll
        for (int j = 0; j < 4; ++j) acc[i][j] += a[i] * b[j];
    }
  }
#pragma unroll
  for (int i = 0; i < 4; ++i) {
    float4 o = make_float4(acc[i][0], acc[i][1], acc[i][2], acc[i][3]);
    *(float4*)&C[(size_t)(m0 + ty * 4 + i) * N + n0 + tx * 4] = o;
  }
}

// Batched Q/K/V projection (768 blocks -> 3 blocks/CU; validated r10).
__global__ __launch_bounds__(256) void gemm_qkv(const float* __restrict__ x,
                                                const float* __restrict__ wq,
                                                const float* __restrict__ wk,
                                                const float* __restrict__ wv,
                                                float* __restrict__ Qb,
                                                float* __restrict__ Kb,
                                                float* __restrict__ Vb) {
  __shared__ float As[32][68];
  __shared__ float Bs[32][68];
  const int z = blockIdx.z;
  const float* B = (z == 0) ? wq : (z == 1) ? wk : wv;
  float*       C = (z == 0) ? Qb : (z == 1) ? Kb : Vb;
  gemm_nt_body(x, B, C, HIDDEN, HIDDEN, blockIdx.x * 64, blockIdx.y * 64, As, Bs);
}

// Split-K=2 output GEMM: 512 blocks (2/CU vs 1/CU). Each z-half sums its K
// range sequentially, then atomicAdd onto memset-zeroed C. Two commutative
// fp32 adds -> bit-deterministic result.
__global__ __launch_bounds__(256) void gemm_nt_sk2(const float* __restrict__ A,
                                                   const float* __restrict__ B,
                                                   float* __restrict__ C,
                                                   int M, int N, int K) {
  __shared__ float As[32][68];
  __shared__ float Bs[32][68];
  const int m0 = blockIdx.x * 64, n0 = blockIdx.y * 64;
  const int kb0 = blockIdx.z * (K / 2), kb1 = kb0 + K / 2;
  const int t  = threadIdx.x;
  const int tx = t & 15, ty = t >> 4;
  const int rr = t >> 3, cc = (t & 7) << 2;
  float acc[4][4] = {};

  float4 fa0 = *(const float4*)&A[(size_t)(m0 + rr)      * K + kb0 + cc];
  float4 fa1 = *(const float4*)&A[(size_t)(m0 + rr + 32) * K + kb0 + cc];
  float4 fb0 = *(const float4*)&B[(size_t)(n0 + rr)      * K + kb0 + cc];
  float4 fb1 = *(const float4*)&B[(size_t)(n0 + rr + 32) * K + kb0 + cc];

  for (int k0 = kb0; k0 < kb1; k0 += 32) {
    __syncthreads();
    As[cc + 0][rr] = fa0.x; As[cc + 1][rr] = fa0.y; As[cc + 2][rr] = fa0.z; As[cc + 3][rr] = fa0.w;
    As[cc + 0][rr + 32] = fa1.x; As[cc + 1][rr + 32] = fa1.y; As[cc + 2][rr + 32] = fa1.z; As[cc + 3][rr + 32] = fa1.w;
    Bs[cc + 0][rr] = fb0.x; Bs[cc + 1][rr] = fb0.y; Bs[cc + 2][rr] = fb0.z; Bs[cc + 3][rr] = fb0.w;
    Bs[cc + 0][rr + 32] = fb1.x; Bs[cc + 1][rr + 32] = fb1.y; Bs[cc + 2][rr + 32] = fb1.z; Bs[cc + 3][rr + 32] = fb1.w;
    __syncthreads();
    if (k0 + 32 < kb1) {
      fa0 = *(const float4*)&A[(size_t)(m0 + rr)      * K + k0 + 32 + cc];
      fa1 = *(const float4*)&A[(size_t)(m0 + rr + 32) * K + k0 + 32 + cc];
      fb0 = *(const float4*)&B[(size_t)(n0 + rr)      * K + k0 + 32 + cc];
      fb1 = *(const float4*)&B[(size_t)(n0 + rr + 32) * K + k0 + 32 + cc];
    }
#pragma unroll
    for (int kk = 0; kk < 32; ++kk) {
      const float4 a4 = *(const float4*)&As[kk][ty * 4];
      const float4 b4 = *(const float4*)&Bs[kk][tx * 4];
      const float a[4] = {a4.x, a4.y, a4.z, a4.w};
      const float b[4] = {b4.x, b4.y, b4.z, b4.w};
#pragma unroll
      for (int i = 0; i < 4; ++i)
#pragma unroll
        for (int j = 0; j < 4; ++j) acc[i][j] += a[i] * b[j];
    }
  }
#pragma unroll
  for (int i = 0; i < 4; ++i)
#pragma unroll
    for (int j = 0; j < 4; ++j)
      atomicAdd(&C[(size_t)(m0 + ty * 4 + i) * N + n0 + tx * 4 + j], acc[i][j]);
}

// Fused importance+score GEMM. Tile 128q x 64k, depth 64. (validated)
__global__ __launch_bounds__(256) void score_gemm(const float* __restrict__ Q,
                                                  const float* __restrict__ K,
                                                  unsigned* __restrict__ impu,
                                                  _Float16* __restrict__ sch) {
  __shared__ float Qs[64][132];
  __shared__ float Ks[64][68];
  const int bid  = blockIdx.x;
  const int h    = bid & (NHEAD - 1);
  const int tile = bid >> 3;
  const int q0   = (tile & 15) * 128;
  const int k0   = (tile >> 4) * 64;
  const int t  = threadIdx.x;
  const int tx = t & 15, ty = t >> 4;

#pragma unroll
  for (int s = 0; s < 8; ++s) {
    const int sf = s * 256 + t;
    const int r = sf >> 4, c = (sf & 15) * 4;
    const float4 f = *(const float4*)&Q[(size_t)(q0 + r) * HIDDEN + h * DHEAD + c];
    Qs[c + 0][r] = f.x; Qs[c + 1][r] = f.y; Qs[c + 2][r] = f.z; Qs[c + 3][r] = f.w;
  }
#pragma unroll
  for (int s = 0; s < 4; ++s) {
    const int sf = s * 256 + t;
    const int r = sf >> 4, c = (sf & 15) * 4;
    const float4 f = *(const float4*)&K[(size_t)(k0 + r) * HIDDEN + h * DHEAD + c];
    Ks[c + 0][r] = f.x; Ks[c + 1][r] = f.y; Ks[c + 2][r] = f.z; Ks[c + 3][r] = f.w;
  }
  __syncthreads();

  float acc[8][4] = {};
#pragma unroll
  for (int d = 0; d < 32; ++d) {
    const float4 aa = *(const float4*)&Qs[d][ty * 8];
    const float4 ab = *(const float4*)&Qs[d][ty * 8 + 4];
    const float4 b4 = *(const float4*)&Ks[d][tx * 4];
    const float a[8] = {aa.x, aa.y, aa.z, aa.w, ab.x, ab.y, ab.z, ab.w};
    const float b[4] = {b4.x, b4.y, b4.z, b4.w};
#pragma unroll
    for (int i = 0; i < 8; ++i)
#pragma unroll
      for (int j = 0; j < 4; ++j) acc[i][j] += a[i] * b[j];
  }
  float simp[8][4];
#pragma unroll
  for (int i = 0; i < 8; ++i)
#pragma unroll
    for (int j = 0; j < 4; ++j) simp[i][j] = acc[i][j];
#pragma unroll
  for (int d = 32; d < 64; ++d) {
    const float4 aa = *(const float4*)&Qs[d][ty * 8];
    const float4 ab = *(const float4*)&Qs[d][ty * 8 + 4];
    const float4 b4 = *(const float4*)&Ks[d][tx * 4];
    const float a[8] = {aa.x, aa.y, aa.z, aa.w, ab.x, ab.y, ab.z, ab.w};
    const float b[4] = {b4.x, b4.y, b4.z, b4.w};
#pragma unroll
    for (int i = 0; i < 8; ++i)
#pragma unroll
      for (int j = 0; j < 4; ++j) acc[i][j] += a[i] * b[j];
  }

#pragma unroll
  for (int i = 0; i < 8; ++i) {
    const size_t gr = (size_t)(h * S_LEN) + q0 + ty * 8 + i;
    const size_t off = gr * S_LEN + k0 + tx * 4;
    *(uint4*)&impu[off] = make_uint4(mapu(simp[i][0]), mapu(simp[i][1]),
                                     mapu(simp[i][2]), mapu(simp[i][3]));
    H4 pk;
#pragma unroll
    for (int j = 0; j < 4; ++j) pk.h[j] = (_Float16)(acc[i][j] * SCALE_);
    *(uint2*)&sch[off] = pk.u2;
  }
}

// One wave per row. Two-level uniform value-bin select (validated r13).
// NEW: collect via PER-BIN OFFSET ATOMICS -- bins partition the value space
// exactly (monotone binning), so bin>B => selected, bin<B => rejected, only
// bin-B elements compare against T. Replaces the 64-deep serial ballot chain
// with 32 independent LDS atomics. Set identical; within-set order permutes
// (softmax/PV are order-invariant sums).
__global__ __launch_bounds__(512) void fused_select_pv(const unsigned* __restrict__ impu,
                                                       const _Float16* __restrict__ sch,
                                                       const float* __restrict__ V,
                                                       float* __restrict__ AO) {
  __shared__ unsigned hist[ROWS_A][256];           // 8 KB
  __shared__ unsigned offs[ROWS_A][256];           // 8 KB (per-bin placement cursors)
  __shared__ float    sbuf[ROWS_A][NSEL];          // 8 KB (scratch: uint ebuf during select)
  __shared__ unsigned ibuf[ROWS_A][NSEL];          // 8 KB (element offsets idx<<9)
  __shared__ unsigned short eqbuf[ROWS_A][64];     // 1 KB
  __shared__ unsigned rstate[ROWS_A][2];
  __shared__ unsigned cntEq[ROWS_A];

  const int t = threadIdx.x, wv = t >> 6, lane = t & 63;
  const unsigned long long lmask = (1ull << lane) - 1ull;
  const size_t gr = (size_t)blockIdx.x * ROWS_A + wv;   // gr = h*S + q
  const unsigned* rowp  = impu + gr * S_LEN;
  const _Float16* shrow = sch  + gr * S_LEN;

  uint4 u[8];
  H4    s4[8];
#pragma unroll
  for (int j = 0; j < 8; ++j) {
    u[j]     = *(const uint4*)&rowp[j * 256 + lane * 4];
    s4[j].u2 = *(const uint2*)&shrow[j * 256 + lane * 4];
  }
  // element idx for component e of u[j]: j*256 + lane*4 + e

  // ---- wave min/max in mapped domain ----
  unsigned um = u[0].x, uM = u[0].x;
#pragma unroll
  for (int j = 0; j < 8; ++j) {
    um = min(um, min(min(u[j].x, u[j].y), min(u[j].z, u[j].w)));
    uM = max(uM, max(max(u[j].x, u[j].y), max(u[j].z, u[j].w)));
  }
#pragma unroll
  for (int off = 32; off; off >>= 1) {
    um = min(um, (unsigned)__shfl_xor((int)um, off));
    uM = max(uM, (unsigned)__shfl_xor((int)uM, off));
  }

  unsigned bn[8];   // packed level-1 bins: 4 x u8 per u32 (computed once)
  unsigned T, Bsel;
  if (uM == um) {
    T = uM; Bsel = 0;                         // degenerate: all values equal -> all ties
#pragma unroll
    for (int j = 0; j < 8; ++j) bn[j] = 0u;
    if (lane == 0) offs[wv][0] = 0u;
    WAVE_SYNC();
  } else {
    const float vmin  = unmapu(um);
    const float scale = 255.0f / (unmapu(uM) - vmin);

    // ---- level-1 histogram over uniform value bins (bins cached) ----
    *(uint4*)&hist[wv][lane * 4] = make_uint4(0u, 0u, 0u, 0u);
    WAVE_SYNC();
#pragma unroll
    for (int j = 0; j < 8; ++j) {
      const unsigned uu[4] = {u[j].x, u[j].y, u[j].z, u[j].w};
      unsigned pk = 0;
#pragma unroll
      for (int e = 0; e < 4; ++e) {
        int bb = (int)((unmapu(uu[e]) - vmin) * scale);
        bb = bb < 0 ? 0 : (bb > 255 ? 255 : bb);
        pk |= (unsigned)bb << (8 * e);
        atomicAdd(&hist[wv][bb], 1u);
      }
      bn[j] = pk;
    }
    WAVE_SYNC();
    // ---- suffix scan (descending bins) + per-bin start offsets ----
    {
      const int g = 63 - lane;
      const uint4 c4 = *(const uint4*)&hist[wv][4 * g];
      const unsigned c0 = c4.x, c1 = c4.y, c2 = c4.z, c3 = c4.w;
      const unsigned lsum = c0 + c1 + c2 + c3;
      unsigned incl = lsum;
#pragma unroll
      for (int off = 1; off < 64; off <<= 1) {
        unsigned o = __shfl_up(incl, off);
        if (lane >= off) incl += o;
      }
      const unsigned excl = incl - lsum;
      offs[wv][4*g+3] = excl;                    // start[b] = #elements in bins > b
      offs[wv][4*g+2] = excl + c3;
      offs[wv][4*g+1] = excl + c3 + c2;
      offs[wv][4*g+0] = excl + c3 + c2 + c1;
      const unsigned ab3 = excl, ab2 = excl + c3, ab1 = excl + c3 + c2, ab0 = excl + c3 + c2 + c1;
      if (ab3 < NSEL && NSEL <= ab3 + c3) { rstate[wv][0] = 4u*g+3u; rstate[wv][1] = NSEL - ab3; }
      if (ab2 < NSEL && NSEL <= ab2 + c2) { rstate[wv][0] = 4u*g+2u; rstate[wv][1] = NSEL - ab2; }
      if (ab1 < NSEL && NSEL <= ab1 + c1) { rstate[wv][0] = 4u*g+1u; rstate[wv][1] = NSEL - ab1; }
      if (ab0 < NSEL && NSEL <= ab0 + c0) { rstate[wv][0] = 4u*g+0u; rstate[wv][1] = NSEL - ab0; }
    }
    WAVE_SYNC();
    const unsigned B    = rstate[wv][0];
    const unsigned krem = rstate[wv][1];
    const unsigned nb   = hist[wv][B];
    Bsel = B;

    if (nb <= 64) {
      // ---- collect bin-B values via cached bins (ballot-prefix) ----
      unsigned* ebufu = (unsigned*)&sbuf[wv][0];
      unsigned nbase = 0;
#pragma unroll
      for (int j = 0; j < 8; ++j) {
        const unsigned uu[4] = {u[j].x, u[j].y, u[j].z, u[j].w};
#pragma unroll
        for (int e = 0; e < 4; ++e) {
          const bool inb = (((bn[j] >> (8 * e)) & 0xFFu) == B);
          const unsigned long long m = __ballot(inb);
          if (inb) ebufu[nbase + (unsigned)__popcll(m & lmask)] = uu[e];
          nbase += (unsigned)__popcll(m);
        }
      }
      WAVE_SYNC();
      // ---- exact rank-select among nb (<=64) candidates ----
      const unsigned myv = (lane < (int)nb) ? ebufu[lane] : 0u;
      unsigned gtc = 0, eqc = 0;
      for (unsigned jj = 0; jj < nb; ++jj) {
        const unsigned bv = (unsigned)__shfl((int)myv, (int)jj);
        gtc += (bv > myv) ? 1u : 0u;
        eqc += (bv == myv) ? 1u : 0u;
      }
      if (lane < (int)nb && gtc < krem && krem <= gtc + eqc) rstate[wv][0] = myv;
      WAVE_SYNC();
      T = rstate[wv][0];
    } else {
      // ---- level 2 (rare): refine within bin B, global re-reads only ----
      const float vmin1 = vmin; const float scale1 = scale;
      unsigned m2min = 0xFFFFFFFFu, m2max = 0u;
      for (int i = lane; i < S_LEN; i += 64) {
        const unsigned x = rowp[i];
        int bb = (int)((unmapu(x) - vmin1) * scale1);
        bb = bb < 0 ? 0 : (bb > 255 ? 255 : bb);
        if (bb == (int)B) { m2min = min(m2min, x); m2max = max(m2max, x); }
      }
#pragma unroll
      for (int off = 32; off; off >>= 1) {
        m2min = min(m2min, (unsigned)__shfl_xor((int)m2min, off));
        m2max = max(m2max, (unsigned)__shfl_xor((int)m2max, off));
      }
      if (m2max == m2min) {
        T = m2max;
      } else {
        const float vlo2   = unmapu(m2min);
        const float scale2 = 255.0f / (unmapu(m2max) - vlo2);
        *(uint4*)&hist[wv][lane * 4] = make_uint4(0u, 0u, 0u, 0u);
        WAVE_SYNC();
        for (int i = lane; i < S_LEN; i += 64) {
          const unsigned x = rowp[i];
          const float v = unmapu(x);
          int bb = (int)((v - vmin1) * scale1);
          bb = bb < 0 ? 0 : (bb > 255 ? 255 : bb);
          if (bb == (int)B) {
            int b2 = (int)((v - vlo2) * scale2);
            b2 = b2 < 0 ? 0 : (b2 > 255 ? 255 : b2);
            atomicAdd(&hist[wv][b2], 1u);
          }
        }
        WAVE_SYNC();
        {
          const int g = 63 - lane;
          const uint4 c4 = *(const uint4*)&hist[wv][4 * g];
          const unsigned c0 = c4.x, c1 = c4.y, c2 = c4.z, c3 = c4.w;
          const unsigned lsum = c0 + c1 + c2 + c3;
          unsigned incl = lsum;
#pragma unroll
          for (int off = 1; off < 64; off <<= 1) {
            unsigned o = __shfl_up(incl, off);
            if (lane >= off) incl += o;
          }
          const unsigned excl = incl - lsum;
          const unsigned ab3 = excl, ab2 = excl + c3, ab1 = excl + c3 + c2, ab0 = excl + c3 + c2 + c1;
          if (ab3 < krem && krem <= ab3 + c3) { rstate[wv][0] = 4u*g+3u; rstate[wv][1] = krem - ab3; }
          if (ab2 < krem && krem <= ab2 + c2) { rstate[wv][0] = 4u*g+2u; rstate[wv][1] = krem - ab2; }
          if (ab1 < krem && krem <= ab1 + c1) { rstate[wv][0] = 4u*g+1u; rstate[wv][1] = krem - ab1; }
          if (ab0 < krem && krem <= ab0 + c0) { rstate[wv][0] = 4u*g+0u; rstate[wv][1] = krem - ab0; }
        }
        WAVE_SYNC();
        const unsigned B2    = rstate[wv][0];
        const unsigned krem2 = rstate[wv][1];
        const unsigned nb2   = hist[wv][B2];
        if (nb2 <= 64) {
          unsigned* ebufu = (unsigned*)&sbuf[wv][0];
          unsigned nbase = 0;
          for (int i = lane; i < S_LEN; i += 64) {
            const unsigned x = rowp[i];
            const float v = unmapu(x);
            int bb = (int)((v - vmin1) * scale1);
            bb = bb < 0 ? 0 : (bb > 255 ? 255 : bb);
            bool inb = false;
            if (bb == (int)B) {
              int b2 = (int)((v - vlo2) * scale2);
              b2 = b2 < 0 ? 0 : (b2 > 255 ? 255 : b2);
              inb = (b2 == (int)B2);
            }
            const unsigned long long m = __ballot(inb);
            if (inb) ebufu[nbase + (unsigned)__popcll(m & lmask)] = x;
            nbase += (unsigned)__popcll(m);
          }
          WAVE_SYNC();
          const unsigned myv = (lane < (int)nb2) ? ebufu[lane] : 0u;
          unsigned gtc = 0, eqc = 0;
          for (unsigned jj = 0; jj < nb2; ++jj) {
            const unsigned bv = (unsigned)__shfl((int)myv, (int)jj);
            gtc += (bv > myv) ? 1u : 0u;
            eqc += (bv == myv) ? 1u : 0u;
          }
          if (lane < (int)nb2 && gtc < krem2 && krem2 <= gtc + eqc) rstate[wv][0] = myv;
          WAVE_SYNC();
          T = rstate[wv][0];
        } else {
          // ---- ultimate safety: lane-0 serial exact byte radix ----
          if (lane == 0) {
            unsigned pfx = 0, kr = NSEL;
            for (int rb = 3; rb >= 0; --rb) {
              for (int i2 = 0; i2 < 256; ++i2) hist[wv][i2] = 0u;
              for (int i2 = 0; i2 < S_LEN; ++i2) {
                const unsigned x = rowp[i2];
                if (rb == 3 || ((x >> (rb * 8 + 8)) == pfx)) hist[wv][(x >> (rb * 8)) & 0xFF]++;
              }
              unsigned cum = 0, sel = 0;
              for (int bb2 = 255; bb2 >= 0; --bb2) {
                if (kr <= cum + hist[wv][bb2]) { sel = (unsigned)bb2; kr -= cum; break; }
                cum += hist[wv][bb2];
              }
              pfx = (pfx << 8) | sel;
            }
            rstate[wv][0] = pfx;
          }
          WAVE_SYNC();
          T = rstate[wv][0];
        }
      }
    }
  }

  // ---- collect (offset, score): per-bin offset atomics (set-exact) ----
  if (lane == 0) cntEq[wv] = 0;
  WAVE_SYNC();
#pragma unroll
  for (int j = 0; j < 8; ++j) {
    const unsigned uu[4] = {u[j].x, u[j].y, u[j].z, u[j].w};
#pragma unroll
    for (int e = 0; e < 4; ++e) {
      const unsigned v = uu[e];
      const int i = j * 256 + lane * 4 + e;
      const unsigned b = (bn[j] >> (8 * e)) & 0xFFu;
      if (b > Bsel) {                            // strictly above boundary bin: selected
        const unsigned p = atomicAdd(&offs[wv][b], 1u);
        ibuf[wv][p] = (unsigned)i << 9;
        sbuf[wv][p] = (float)s4[j].h[e];
      } else if (b == Bsel) {
        if (v > T) {
          const unsigned p = atomicAdd(&offs[wv][Bsel], 1u);
          ibuf[wv][p] = (unsigned)i << 9;
          sbuf[wv][p] = (float)s4[j].h[e];
        } else if (v == T) {
          const unsigned p = atomicAdd(&cntEq[wv], 1u);
          if (p < 64) eqbuf[wv][p] = (unsigned short)i;
        }
      }
    }
  }
  WAVE_SYNC();
  const unsigned ngt = offs[wv][Bsel];           // = start[B] + gt-in-B
  const unsigned ne  = cntEq[wv];
  const unsigned need = NSEL - ngt;
  if (ne == need && ne <= 64) {                  // all ties taken: order irrelevant
    for (unsigned j = lane; j < ne; j += 64) {
      const unsigned short ix = eqbuf[wv][j];
      ibuf[wv][ngt + j] = (unsigned)ix << 9;
      sbuf[wv][ngt + j] = (float)shrow[ix];
    }
  } else if (lane == 0) {
    if (ne <= 64) {                              // eqbuf scrambled but complete: sort, take lowest
      for (unsigned a = 1; a < ne; ++a) {
        unsigned short kv = eqbuf[wv][a]; int bp = (int)a;
        while (bp > 0 && eqbuf[wv][bp - 1] > kv) { eqbuf[wv][bp] = eqbuf[wv][bp - 1]; --bp; }
        eqbuf[wv][bp] = kv;
      }
      for (unsigned j = 0; j < need; ++j) {
        const unsigned short ix = eqbuf[wv][j];
        ibuf[wv][ngt + j] = (unsigned)ix << 9;
        sbuf[wv][ngt + j] = (float)shrow[ix];
      }
    } else {                                     // pathological: serial ascending scan
      unsigned taken = 0;
      for (int i = 0; i < S_LEN && taken < need; ++i)
        if (rowp[i] == T) { ibuf[wv][ngt + taken] = (unsigned)i << 9; sbuf[wv][ngt + taken] = (float)shrow[i]; ++taken; }
    }
  }
  WAVE_SYNC();

  // ---- softmax over the 256 selected scores ----
  float sc[4];
#pragma unroll
  for (int m = 0; m < 4; ++m) sc[m] = sbuf[wv][lane * 4 + m];
  float mx = fmaxf(fmaxf(sc[0], sc[1]), fmaxf(sc[2], sc[3]));
#pragma unroll
  for (int off = 32; off; off >>= 1) mx = fmaxf(mx, __shfl_xor(mx, off));
  float zs = 0.f;
#pragma unroll
  for (int m = 0; m < 4; ++m) { sc[m] = expf(sc[m] - mx); zs += sc[m]; }
#pragma unroll
  for (int off = 32; off; off >>= 1) zs += __shfl_xor(zs, off);
  const float rz = 1.0f / zs;
  *(float4*)&sbuf[wv][lane * 4] = make_float4(sc[0], sc[1], sc[2], sc[3]);
  WAVE_SYNC();

  // ---- PV: wave-contiguous 256B V-row reads; offsets precomputed ----
  const int h = (int)(gr >> 11), q = (int)(gr & (S_LEN - 1));
  const float* Vhl = V + h * DHEAD + lane;
  float outv = 0.f;
#pragma unroll 8
  for (int j = 0; j < NSEL; j += 4) {
    const uint4  id4 = *(const uint4*)&ibuf[wv][j];
    const float4 w4  = *(const float4*)&sbuf[wv][j];
    outv += w4.x * Vhl[id4.x];
    outv += w4.y * Vhl[id4.y];
    outv += w4.z * Vhl[id4.z];
    outv += w4.w * Vhl[id4.w];
  }
  AO[(size_t)q * HIDDEN + h * DHEAD + lane] = outv * rz;
}

extern "C" void kernel_launch(void* const* d_in, const int* in_sizes, int n_in,
                              void* d_out, int out_size, void* d_ws, size_t ws_size,
                              hipStream_t stream) {
  const float* x  = (const float*)d_in[0];
  const float* wq = (const float*)d_in[1];
  const float* wk = (const float*)d_in[2];
  const float* wv = (const float*)d_in[3];
  const float* wo = (const float*)d_in[4];
  float* out = (float*)d_out;

  float* Qb = (float*)d_ws;
  float* Kb = Qb + (size_t)S_LEN * HIDDEN;
  float* Vb = Kb + (size_t)S_LEN * HIDDEN;
  float* AO = Vb + (size_t)S_LEN * HIDDEN;
  void*  tail = (void*)(AO + (size_t)S_LEN * HIDDEN);

  const size_t elems = (size_t)NHEAD * S_LEN * S_LEN;
  unsigned* impu = (unsigned*)tail;
  _Float16* sch  = (_Float16*)(impu + elems);

  gemm_qkv<<<dim3(S_LEN / 64, HIDDEN / 64, 3), 256, 0, stream>>>(x, wq, wk, wv, Qb, Kb, Vb);
  score_gemm<<<dim3(NHEAD * 16 * 32), 256, 0, stream>>>(Qb, Kb, impu, sch);
  fused_select_pv<<<dim3(NHEAD * S_LEN / ROWS_A), 512, 0, stream>>>(impu, sch, Vb, AO);
  hipMemsetAsync(out, 0, (size_t)S_LEN * HIDDEN * sizeof(float), stream);
  gemm_nt_sk2<<<dim3(S_LEN / 64, HIDDEN / 64, 2), 256, 0, stream>>>(AO, wo, out, S_LEN, HIDDEN, HIDDEN);
}

// Round 17
// 239.361 us; speedup vs baseline: 1.1715x; 1.1715x over previous
//
#include <hip/hip_runtime.h>

#define S_LEN  2048
#define HIDDEN 512
#define NHEAD  8
#define DHEAD  64
#define NSEL   256
#define ROWS_A 8
#define SCALE_ 0.125f

// intra-wave LDS producer->consumer sync (lockstep lanes + drain LDS queue)
#define WAVE_SYNC() __asm__ volatile("s_waitcnt lgkmcnt(0)" ::: "memory")

// monotone float->uint mapping (ascending float == ascending uint)
__device__ __forceinline__ unsigned mapu(float f) {
  unsigned u = __float_as_uint(f);
  return (u & 0x80000000u) ? ~u : (u | 0x80000000u);
}
// inverse of mapu
__device__ __forceinline__ float unmapu(unsigned x) {
  return __uint_as_float((x & 0x80000000u) ? (x & 0x7FFFFFFFu) : ~x);
}

union H4 { _Float16 h[4]; uint2 u2; };   // 4 packed fp16 <-> 8B

// ---- VALIDATED 256-thread GEMM body (r10-r15): 64x64 tile, 4x4 micro,
// double-buffered register staging.
__device__ __forceinline__ void gemm_nt_body(const float* __restrict__ A,
                                             const float* __restrict__ B,
                                             float* __restrict__ C,
                                             int K, int N, int m0, int n0,
                                             float (*As)[68], float (*Bs)[68]) {
  const int t  = threadIdx.x;
  const int tx = t & 15, ty = t >> 4;
  const int rr = t >> 3, cc = (t & 7) << 2;
  float acc[4][4] = {};

  float4 fa0 = *(const float4*)&A[(size_t)(m0 + rr)      * K + cc];
  float4 fa1 = *(const float4*)&A[(size_t)(m0 + rr + 32) * K + cc];
  float4 fb0 = *(const float4*)&B[(size_t)(n0 + rr)      * K + cc];
  float4 fb1 = *(const float4*)&B[(size_t)(n0 + rr + 32) * K + cc];

  for (int k0 = 0; k0 < K; k0 += 32) {
    __syncthreads();
    As[cc + 0][rr] = fa0.x; As[cc + 1][rr] = fa0.y; As[cc + 2][rr] = fa0.z; As[cc + 3][rr] = fa0.w;
    As[cc + 0][rr + 32] = fa1.x; As[cc + 1][rr + 32] = fa1.y; As[cc + 2][rr + 32] = fa1.z; As[cc + 3][rr + 32] = fa1.w;
    Bs[cc + 0][rr] = fb0.x; Bs[cc + 1][rr] = fb0.y; Bs[cc + 2][rr] = fb0.z; Bs[cc + 3][rr] = fb0.w;
    Bs[cc + 0][rr + 32] = fb1.x; Bs[cc + 1][rr + 32] = fb1.y; Bs[cc + 2][rr + 32] = fb1.z; Bs[cc + 3][rr + 32] = fb1.w;
    __syncthreads();
    if (k0 + 32 < K) {
      fa0 = *(const float4*)&A[(size_t)(m0 + rr)      * K + k0 + 32 + cc];
      fa1 = *(const float4*)&A[(size_t)(m0 + rr + 32) * K + k0 + 32 + cc];
      fb0 = *(const float4*)&B[(size_t)(n0 + rr)      * K + k0 + 32 + cc];
      fb1 = *(const float4*)&B[(size_t)(n0 + rr + 32) * K + k0 + 32 + cc];
    }
#pragma unroll
    for (int kk = 0; kk < 32; ++kk) {
      const float4 a4 = *(const float4*)&As[kk][ty * 4];
      const float4 b4 = *(const float4*)&Bs[kk][tx * 4];
      const float a[4] = {a4.x, a4.y, a4.z, a4.w};
      const float b[4] = {b4.x, b4.y, b4.z, b4.w};
#pragma unroll
      for (int i = 0; i < 4; ++i)
#pragma unroll
        for (int j = 0; j < 4; ++j) acc[i][j] += a[i] * b[j];
    }
  }
#pragma unroll
  for (int i = 0; i < 4; ++i) {
    float4 o = make_float4(acc[i][0], acc[i][1], acc[i][2], acc[i][3]);
    *(float4*)&C[(size_t)(m0 + ty * 4 + i) * N + n0 + tx * 4] = o;
  }
}

// Batched Q/K/V projection (768 blocks -> 3 blocks/CU; validated r10).
__global__ __launch_bounds__(256) void gemm_qkv(const float* __restrict__ x,
                                                const float* __restrict__ wq,
                                                const float* __restrict__ wk,
                                                const float* __restrict__ wv,
                                                float* __restrict__ Qb,
                                                float* __restrict__ Kb,
                                                float* __restrict__ Vb) {
  __shared__ float As[32][68];
  __shared__ float Bs[32][68];
  const int z = blockIdx.z;
  const float* B = (z == 0) ? wq : (z == 1) ? wk : wv;
  float*       C = (z == 0) ? Qb : (z == 1) ? Kb : Vb;
  gemm_nt_body(x, B, C, HIDDEN, HIDDEN, blockIdx.x * 64, blockIdx.y * 64, As, Bs);
}

// Split-K=2 output GEMM: 512 blocks (2/CU vs 1/CU). Each z-half sums its K
// range sequentially, then atomicAdd onto memset-zeroed C (2 commutative
// fp32 adds -> deterministic).
__global__ __launch_bounds__(256) void gemm_nt_sk2(const float* __restrict__ A,
                                                   const float* __restrict__ B,
                                                   float* __restrict__ C,
                                                   int M, int N, int K) {
  __shared__ float As[32][68];
  __shared__ float Bs[32][68];
  const int m0 = blockIdx.x * 64, n0 = blockIdx.y * 64;
  const int kb0 = blockIdx.z * (K / 2), kb1 = kb0 + K / 2;
  const int t  = threadIdx.x;
  const int tx = t & 15, ty = t >> 4;
  const int rr = t >> 3, cc = (t & 7) << 2;
  float acc[4][4] = {};

  float4 fa0 = *(const float4*)&A[(size_t)(m0 + rr)      * K + kb0 + cc];
  float4 fa1 = *(const float4*)&A[(size_t)(m0 + rr + 32) * K + kb0 + cc];
  float4 fb0 = *(const float4*)&B[(size_t)(n0 + rr)      * K + kb0 + cc];
  float4 fb1 = *(const float4*)&B[(size_t)(n0 + rr + 32) * K + kb0 + cc];

  for (int k0 = kb0; k0 < kb1; k0 += 32) {
    __syncthreads();
    As[cc + 0][rr] = fa0.x; As[cc + 1][rr] = fa0.y; As[cc + 2][rr] = fa0.z; As[cc + 3][rr] = fa0.w;
    As[cc + 0][rr + 32] = fa1.x; As[cc + 1][rr + 32] = fa1.y; As[cc + 2][rr + 32] = fa1.z; As[cc + 3][rr + 32] = fa1.w;
    Bs[cc + 0][rr] = fb0.x; Bs[cc + 1][rr] = fb0.y; Bs[cc + 2][rr] = fb0.z; Bs[cc + 3][rr] = fb0.w;
    Bs[cc + 0][rr + 32] = fb1.x; Bs[cc + 1][rr + 32] = fb1.y; Bs[cc + 2][rr + 32] = fb1.z; Bs[cc + 3][rr + 32] = fb1.w;
    __syncthreads();
    if (k0 + 32 < kb1) {
      fa0 = *(const float4*)&A[(size_t)(m0 + rr)      * K + k0 + 32 + cc];
      fa1 = *(const float4*)&A[(size_t)(m0 + rr + 32) * K + k0 + 32 + cc];
      fb0 = *(const float4*)&B[(size_t)(n0 + rr)      * K + k0 + 32 + cc];
      fb1 = *(const float4*)&B[(size_t)(n0 + rr + 32) * K + k0 + 32 + cc];
    }
#pragma unroll
    for (int kk = 0; kk < 32; ++kk) {
      const float4 a4 = *(const float4*)&As[kk][ty * 4];
      const float4 b4 = *(const float4*)&Bs[kk][tx * 4];
      const float a[4] = {a4.x, a4.y, a4.z, a4.w};
      const float b[4] = {b4.x, b4.y, b4.z, b4.w};
#pragma unroll
      for (int i = 0; i < 4; ++i)
#pragma unroll
        for (int j = 0; j < 4; ++j) acc[i][j] += a[i] * b[j];
    }
  }
#pragma unroll
  for (int i = 0; i < 4; ++i)
#pragma unroll
    for (int j = 0; j < 4; ++j)
      atomicAdd(&C[(size_t)(m0 + ty * 4 + i) * N + n0 + tx * 4 + j], acc[i][j]);
}

// Fused importance+score GEMM. Tile 128q x 64k, depth 64. (validated)
__global__ __launch_bounds__(256) void score_gemm(const float* __restrict__ Q,
                                                  const float* __restrict__ K,
                                                  unsigned* __restrict__ impu,
                                                  _Float16* __restrict__ sch) {
  __shared__ float Qs[64][132];
  __shared__ float Ks[64][68];
  const int bid  = blockIdx.x;
  const int h    = bid & (NHEAD - 1);
  const int tile = bid >> 3;
  const int q0   = (tile & 15) * 128;
  const int k0   = (tile >> 4) * 64;
  const int t  = threadIdx.x;
  const int tx = t & 15, ty = t >> 4;

#pragma unroll
  for (int s = 0; s < 8; ++s) {
    const int sf = s * 256 + t;
    const int r = sf >> 4, c = (sf & 15) * 4;
    const float4 f = *(const float4*)&Q[(size_t)(q0 + r) * HIDDEN + h * DHEAD + c];
    Qs[c + 0][r] = f.x; Qs[c + 1][r] = f.y; Qs[c + 2][r] = f.z; Qs[c + 3][r] = f.w;
  }
#pragma unroll
  for (int s = 0; s < 4; ++s) {
    const int sf = s * 256 + t;
    const int r = sf >> 4, c = (sf & 15) * 4;
    const float4 f = *(const float4*)&K[(size_t)(k0 + r) * HIDDEN + h * DHEAD + c];
    Ks[c + 0][r] = f.x; Ks[c + 1][r] = f.y; Ks[c + 2][r] = f.z; Ks[c + 3][r] = f.w;
  }
  __syncthreads();

  float acc[8][4] = {};
#pragma unroll
  for (int d = 0; d < 32; ++d) {
    const float4 aa = *(const float4*)&Qs[d][ty * 8];
    const float4 ab = *(const float4*)&Qs[d][ty * 8 + 4];
    const float4 b4 = *(const float4*)&Ks[d][tx * 4];
    const float a[8] = {aa.x, aa.y, aa.z, aa.w, ab.x, ab.y, ab.z, ab.w};
    const float b[4] = {b4.x, b4.y, b4.z, b4.w};
#pragma unroll
    for (int i = 0; i < 8; ++i)
#pragma unroll
      for (int j = 0; j < 4; ++j) acc[i][j] += a[i] * b[j];
  }
  float simp[8][4];
#pragma unroll
  for (int i = 0; i < 8; ++i)
#pragma unroll
    for (int j = 0; j < 4; ++j) simp[i][j] = acc[i][j];
#pragma unroll
  for (int d = 32; d < 64; ++d) {
    const float4 aa = *(const float4*)&Qs[d][ty * 8];
    const float4 ab = *(const float4*)&Qs[d][ty * 8 + 4];
    const float4 b4 = *(const float4*)&Ks[d][tx * 4];
    const float a[8] = {aa.x, aa.y, aa.z, aa.w, ab.x, ab.y, ab.z, ab.w};
    const float b[4] = {b4.x, b4.y, b4.z, b4.w};
#pragma unroll
    for (int i = 0; i < 8; ++i)
#pragma unroll
      for (int j = 0; j < 4; ++j) acc[i][j] += a[i] * b[j];
  }

#pragma unroll
  for (int i = 0; i < 8; ++i) {
    const size_t gr = (size_t)(h * S_LEN) + q0 + ty * 8 + i;
    const size_t off = gr * S_LEN + k0 + tx * 4;
    *(uint4*)&impu[off] = make_uint4(mapu(simp[i][0]), mapu(simp[i][1]),
                                     mapu(simp[i][2]), mapu(simp[i][3]));
    H4 pk;
#pragma unroll
    for (int j = 0; j < 4; ++j) pk.h[j] = (_Float16)(acc[i][j] * SCALE_);
    *(uint2*)&sch[off] = pk.u2;
  }
}

// One wave per row. Two-level uniform value-bin select with cached packed
// bins + ballot collect (VALIDATED r13/r15 form: 86us, 26112 LDS, Occ 37%).
// r16's per-bin-offset variant (+8KB LDS) dropped occupancy 37->22: reverted.
__global__ __launch_bounds__(512) void fused_select_pv(const unsigned* __restrict__ impu,
                                                       const _Float16* __restrict__ sch,
                                                       const float* __restrict__ V,
                                                       float* __restrict__ AO) {
  __shared__ unsigned hist[ROWS_A][256];           // 8 KB
  __shared__ float    sbuf[ROWS_A][NSEL];          // 8 KB (scratch: uint ebuf during select)
  __shared__ unsigned ibuf[ROWS_A][NSEL];          // 8 KB (element offsets idx<<9)
  __shared__ unsigned short eqbuf[ROWS_A][64];     // 1 KB
  __shared__ unsigned rstate[ROWS_A][2];

  const int t = threadIdx.x, wv = t >> 6, lane = t & 63;
  const unsigned long long lmask = (1ull << lane) - 1ull;
  const size_t gr = (size_t)blockIdx.x * ROWS_A + wv;   // gr = h*S + q
  const unsigned* rowp  = impu + gr * S_LEN;
  const _Float16* shrow = sch  + gr * S_LEN;

  uint4 u[8];
  H4    s4[8];
#pragma unroll
  for (int j = 0; j < 8; ++j) {
    u[j]     = *(const uint4*)&rowp[j * 256 + lane * 4];
    s4[j].u2 = *(const uint2*)&shrow[j * 256 + lane * 4];
  }
  // element idx for component e of u[j]: j*256 + lane*4 + e

  // ---- wave min/max in mapped domain ----
  unsigned um = u[0].x, uM = u[0].x;
#pragma unroll
  for (int j = 0; j < 8; ++j) {
    um = min(um, min(min(u[j].x, u[j].y), min(u[j].z, u[j].w)));
    uM = max(uM, max(max(u[j].x, u[j].y), max(u[j].z, u[j].w)));
  }
#pragma unroll
  for (int off = 32; off; off >>= 1) {
    um = min(um, (unsigned)__shfl_xor((int)um, off));
    uM = max(uM, (unsigned)__shfl_xor((int)uM, off));
  }

  unsigned bn[8];   // packed level-1 bins: 4 x u8 per u32 (computed once)
  unsigned T;
  if (uM == um) {
    T = uM;                                   // degenerate: all values equal
  } else {
    const float vmin  = unmapu(um);
    const float scale = 255.0f / (unmapu(uM) - vmin);

    // ---- level-1 histogram over uniform value bins (bins cached) ----
    *(uint4*)&hist[wv][lane * 4] = make_uint4(0u, 0u, 0u, 0u);
    WAVE_SYNC();
#pragma unroll
    for (int j = 0; j < 8; ++j) {
      const unsigned uu[4] = {u[j].x, u[j].y, u[j].z, u[j].w};
      unsigned pk = 0;
#pragma unroll
      for (int e = 0; e < 4; ++e) {
        int bb = (int)((unmapu(uu[e]) - vmin) * scale);
        bb = bb < 0 ? 0 : (bb > 255 ? 255 : bb);
        pk |= (unsigned)bb << (8 * e);
        atomicAdd(&hist[wv][bb], 1u);
      }
      bn[j] = pk;
    }
    WAVE_SYNC();
    // ---- suffix scan (descending bins) ----
    {
      const int g = 63 - lane;
      const uint4 c4 = *(const uint4*)&hist[wv][4 * g];
      const unsigned c0 = c4.x, c1 = c4.y, c2 = c4.z, c3 = c4.w;
      const unsigned lsum = c0 + c1 + c2 + c3;
      unsigned incl = lsum;
#pragma unroll
      for (int off = 1; off < 64; off <<= 1) {
        unsigned o = __shfl_up(incl, off);
        if (lane >= off) incl += o;
      }
      const unsigned excl = incl - lsum;
      const unsigned ab3 = excl, ab2 = excl + c3, ab1 = excl + c3 + c2, ab0 = excl + c3 + c2 + c1;
      if (ab3 < NSEL && NSEL <= ab3 + c3) { rstate[wv][0] = 4u*g+3u; rstate[wv][1] = NSEL - ab3; }
      if (ab2 < NSEL && NSEL <= ab2 + c2) { rstate[wv][0] = 4u*g+2u; rstate[wv][1] = NSEL - ab2; }
      if (ab1 < NSEL && NSEL <= ab1 + c1) { rstate[wv][0] = 4u*g+1u; rstate[wv][1] = NSEL - ab1; }
      if (ab0 < NSEL && NSEL <= ab0 + c0) { rstate[wv][0] = 4u*g+0u; rstate[wv][1] = NSEL - ab0; }
    }
    WAVE_SYNC();
    const unsigned B    = rstate[wv][0];
    const unsigned krem = rstate[wv][1];
    const unsigned nb   = hist[wv][B];

    if (nb <= 64) {
      // ---- collect bin-B values via cached bins (ballot-prefix) ----
      unsigned* ebufu = (unsigned*)&sbuf[wv][0];
      unsigned nbase = 0;
#pragma unroll
      for (int j = 0; j < 8; ++j) {
        const unsigned uu[4] = {u[j].x, u[j].y, u[j].z, u[j].w};
#pragma unroll
        for (int e = 0; e < 4; ++e) {
          const bool inb = (((bn[j] >> (8 * e)) & 0xFFu) == B);
          const unsigned long long m = __ballot(inb);
          if (inb) ebufu[nbase + (unsigned)__popcll(m & lmask)] = uu[e];
          nbase += (unsigned)__popcll(m);
        }
      }
      WAVE_SYNC();
      // ---- exact rank-select among nb (<=64) candidates ----
      const unsigned myv = (lane < (int)nb) ? ebufu[lane] : 0u;
      unsigned gtc = 0, eqc = 0;
      for (unsigned jj = 0; jj < nb; ++jj) {
        const unsigned bv = (unsigned)__shfl((int)myv, (int)jj);
        gtc += (bv > myv) ? 1u : 0u;
        eqc += (bv == myv) ? 1u : 0u;
      }
      if (lane < (int)nb && gtc < krem && krem <= gtc + eqc) rstate[wv][0] = myv;
      WAVE_SYNC();
      T = rstate[wv][0];
    } else {
      // ---- level 2 (rare): refine within bin B, global re-reads only ----
      unsigned m2min = 0xFFFFFFFFu, m2max = 0u;
      for (int i = lane; i < S_LEN; i += 64) {
        const unsigned x = rowp[i];
        int bb = (int)((unmapu(x) - vmin) * scale);
        bb = bb < 0 ? 0 : (bb > 255 ? 255 : bb);
        if (bb == (int)B) { m2min = min(m2min, x); m2max = max(m2max, x); }
      }
#pragma unroll
      for (int off = 32; off; off >>= 1) {
        m2min = min(m2min, (unsigned)__shfl_xor((int)m2min, off));
        m2max = max(m2max, (unsigned)__shfl_xor((int)m2max, off));
      }
      if (m2max == m2min) {
        T = m2max;
      } else {
        const float vlo2   = unmapu(m2min);
        const float scale2 = 255.0f / (unmapu(m2max) - vlo2);
        *(uint4*)&hist[wv][lane * 4] = make_uint4(0u, 0u, 0u, 0u);
        WAVE_SYNC();
        for (int i = lane; i < S_LEN; i += 64) {
          const unsigned x = rowp[i];
          const float v = unmapu(x);
          int bb = (int)((v - vmin) * scale);
          bb = bb < 0 ? 0 : (bb > 255 ? 255 : bb);
          if (bb == (int)B) {
            int b2 = (int)((v - vlo2) * scale2);
            b2 = b2 < 0 ? 0 : (b2 > 255 ? 255 : b2);
            atomicAdd(&hist[wv][b2], 1u);
          }
        }
        WAVE_SYNC();
        {
          const int g = 63 - lane;
          const uint4 c4 = *(const uint4*)&hist[wv][4 * g];
          const unsigned c0 = c4.x, c1 = c4.y, c2 = c4.z, c3 = c4.w;
          const unsigned lsum = c0 + c1 + c2 + c3;
          unsigned incl = lsum;
#pragma unroll
          for (int off = 1; off < 64; off <<= 1) {
            unsigned o = __shfl_up(incl, off);
            if (lane >= off) incl += o;
          }
          const unsigned excl = incl - lsum;
          const unsigned ab3 = excl, ab2 = excl + c3, ab1 = excl + c3 + c2, ab0 = excl + c3 + c2 + c1;
          if (ab3 < krem && krem <= ab3 + c3) { rstate[wv][0] = 4u*g+3u; rstate[wv][1] = krem - ab3; }
          if (ab2 < krem && krem <= ab2 + c2) { rstate[wv][0] = 4u*g+2u; rstate[wv][1] = krem - ab2; }
          if (ab1 < krem && krem <= ab1 + c1) { rstate[wv][0] = 4u*g+1u; rstate[wv][1] = krem - ab1; }
          if (ab0 < krem && krem <= ab0 + c0) { rstate[wv][0] = 4u*g+0u; rstate[wv][1] = krem - ab0; }
        }
        WAVE_SYNC();
        const unsigned B2    = rstate[wv][0];
        const unsigned krem2 = rstate[wv][1];
        const unsigned nb2   = hist[wv][B2];
        if (nb2 <= 64) {
          unsigned* ebufu = (unsigned*)&sbuf[wv][0];
          unsigned nbase = 0;
          for (int i = lane; i < S_LEN; i += 64) {
            const unsigned x = rowp[i];
            const float v = unmapu(x);
            int bb = (int)((v - vmin) * scale);
            bb = bb < 0 ? 0 : (bb > 255 ? 255 : bb);
            bool inb = false;
            if (bb == (int)B) {
              int b2 = (int)((v - vlo2) * scale2);
              b2 = b2 < 0 ? 0 : (b2 > 255 ? 255 : b2);
              inb = (b2 == (int)B2);
            }
            const unsigned long long m = __ballot(inb);
            if (inb) ebufu[nbase + (unsigned)__popcll(m & lmask)] = x;
            nbase += (unsigned)__popcll(m);
          }
          WAVE_SYNC();
          const unsigned myv = (lane < (int)nb2) ? ebufu[lane] : 0u;
          unsigned gtc = 0, eqc = 0;
          for (unsigned jj = 0; jj < nb2; ++jj) {
            const unsigned bv = (unsigned)__shfl((int)myv, (int)jj);
            gtc += (bv > myv) ? 1u : 0u;
            eqc += (bv == myv) ? 1u : 0u;
          }
          if (lane < (int)nb2 && gtc < krem2 && krem2 <= gtc + eqc) rstate[wv][0] = myv;
          WAVE_SYNC();
          T = rstate[wv][0];
        } else {
          // ---- ultimate safety: lane-0 serial exact byte radix ----
          if (lane == 0) {
            unsigned pfx = 0, kr = NSEL;
            for (int rb = 3; rb >= 0; --rb) {
              for (int i2 = 0; i2 < 256; ++i2) hist[wv][i2] = 0u;
              for (int i2 = 0; i2 < S_LEN; ++i2) {
                const unsigned x = rowp[i2];
                if (rb == 3 || ((x >> (rb * 8 + 8)) == pfx)) hist[wv][(x >> (rb * 8)) & 0xFF]++;
              }
              unsigned cum = 0, sel = 0;
              for (int bb2 = 255; bb2 >= 0; --bb2) {
                if (kr <= cum + hist[wv][bb2]) { sel = (unsigned)bb2; kr -= cum; break; }
                cum += hist[wv][bb2];
              }
              pfx = (pfx << 8) | sel;
            }
            rstate[wv][0] = pfx;
          }
          WAVE_SYNC();
          T = rstate[wv][0];
        }
      }
    }
  }

  // ---- collect (offset, score): ballot-prefix (validated form) ----
  unsigned base_gt = 0, base_eq = 0;
#pragma unroll
  for (int j = 0; j < 8; ++j) {
    const unsigned uu[4] = {u[j].x, u[j].y, u[j].z, u[j].w};
#pragma unroll
    for (int e = 0; e < 4; ++e) {
      const unsigned v = uu[e];
      const int i = j * 256 + lane * 4 + e;
      const bool gt = (v > T), eq = (v == T);
      const unsigned long long mg = __ballot(gt);
      const unsigned long long me = __ballot(eq);
      if (gt) {
        const unsigned p = base_gt + (unsigned)__popcll(mg & lmask);
        ibuf[wv][p] = (unsigned)i << 9;       // element offset idx*HIDDEN
        sbuf[wv][p] = (float)s4[j].h[e];
      }
      if (eq) {
        const unsigned p = base_eq + (unsigned)__popcll(me & lmask);
        if (p < 64) eqbuf[wv][p] = (unsigned short)i;   // index-ascending
      }
      base_gt += (unsigned)__popcll(mg);
      base_eq += (unsigned)__popcll(me);
    }
  }
  WAVE_SYNC();
  const unsigned ngt = base_gt, ne = base_eq;
  const unsigned need = NSEL - ngt;
  if (ne == need && ne <= 64) {               // all ties taken: order irrelevant
    for (unsigned j = lane; j < ne; j += 64) {
      const unsigned short ix = eqbuf[wv][j];
      ibuf[wv][ngt + j] = (unsigned)ix << 9;
      sbuf[wv][ngt + j] = (float)shrow[ix];
    }
  } else if (lane == 0) {
    if (ne <= 64) {                           // ties ascending: take lowest `need`
      for (unsigned j = 0; j < need; ++j) {
        const unsigned short ix = eqbuf[wv][j];
        ibuf[wv][ngt + j] = (unsigned)ix << 9;
        sbuf[wv][ngt + j] = (float)shrow[ix];
      }
    } else {                                  // pathological: serial ascending scan
      unsigned taken = 0;
      for (int i = 0; i < S_LEN && taken < need; ++i)
        if (rowp[i] == T) { ibuf[wv][ngt + taken] = (unsigned)i << 9; sbuf[wv][ngt + taken] = (float)shrow[i]; ++taken; }
    }
  }
  WAVE_SYNC();

  // ---- softmax over the 256 selected scores ----
  float sc[4];
#pragma unroll
  for (int m = 0; m < 4; ++m) sc[m] = sbuf[wv][lane * 4 + m];
  float mx = fmaxf(fmaxf(sc[0], sc[1]), fmaxf(sc[2], sc[3]));
#pragma unroll
  for (int off = 32; off; off >>= 1) mx = fmaxf(mx, __shfl_xor(mx, off));
  float zs = 0.f;
#pragma unroll
  for (int m = 0; m < 4; ++m) { sc[m] = expf(sc[m] - mx); zs += sc[m]; }
#pragma unroll
  for (int off = 32; off; off >>= 1) zs += __shfl_xor(zs, off);
  const float rz = 1.0f / zs;
  *(float4*)&sbuf[wv][lane * 4] = make_float4(sc[0], sc[1], sc[2], sc[3]);
  WAVE_SYNC();

  // ---- PV: wave-contiguous 256B V-row reads; offsets precomputed ----
  const int h = (int)(gr >> 11), q = (int)(gr & (S_LEN - 1));
  const float* Vhl = V + h * DHEAD + lane;
  float outv = 0.f;
#pragma unroll 8
  for (int j = 0; j < NSEL; j += 4) {
    const uint4  id4 = *(const uint4*)&ibuf[wv][j];
    const float4 w4  = *(const float4*)&sbuf[wv][j];
    outv += w4.x * Vhl[id4.x];
    outv += w4.y * Vhl[id4.y];
    outv += w4.z * Vhl[id4.z];
    outv += w4.w * Vhl[id4.w];
  }
  AO[(size_t)q * HIDDEN + h * DHEAD + lane] = outv * rz;
}

extern "C" void kernel_launch(void* const* d_in, const int* in_sizes, int n_in,
                              void* d_out, int out_size, void* d_ws, size_t ws_size,
                              hipStream_t stream) {
  const float* x  = (const float*)d_in[0];
  const float* wq = (const float*)d_in[1];
  const float* wk = (const float*)d_in[2];
  const float* wv = (const float*)d_in[3];
  const float* wo = (const float*)d_in[4];
  float* out = (float*)d_out;

  float* Qb = (float*)d_ws;
  float* Kb = Qb + (size_t)S_LEN * HIDDEN;
  float* Vb = Kb + (size_t)S_LEN * HIDDEN;
  float* AO = Vb + (size_t)S_LEN * HIDDEN;
  void*  tail = (void*)(AO + (size_t)S_LEN * HIDDEN);

  const size_t elems = (size_t)NHEAD * S_LEN * S_LEN;
  unsigned* impu = (unsigned*)tail;
  _Float16* sch  = (_Float16*)(impu + elems);

  gemm_qkv<<<dim3(S_LEN / 64, HIDDEN / 64, 3), 256, 0, stream>>>(x, wq, wk, wv, Qb, Kb, Vb);
  score_gemm<<<dim3(NHEAD * 16 * 32), 256, 0, stream>>>(Qb, Kb, impu, sch);
  fused_select_pv<<<dim3(NHEAD * S_LEN / ROWS_A), 512, 0, stream>>>(impu, sch, Vb, AO);
  hipMemsetAsync(out, 0, (size_t)S_LEN * HIDDEN * sizeof(float), stream);
  gemm_nt_sk2<<<dim3(S_LEN / 64, HIDDEN / 64, 2), 256, 0, stream>>>(AO, wo, out, S_LEN, HIDDEN, HIDDEN);
}

// Round 18
// 223.793 us; speedup vs baseline: 1.2530x; 1.0696x over previous
//
#include <hip/hip_runtime.h>

#define S_LEN  2048
#define HIDDEN 512
#define NHEAD  8
#define DHEAD  64
#define NSEL   256
#define ROWS_A 8
#define SCALE_ 0.125f

// intra-wave LDS producer->consumer sync (lockstep lanes + drain LDS queue)
#define WAVE_SYNC() __asm__ volatile("s_waitcnt lgkmcnt(0)" ::: "memory")

// monotone float->uint mapping (ascending float == ascending uint)
__device__ __forceinline__ unsigned mapu(float f) {
  unsigned u = __float_as_uint(f);
  return (u & 0x80000000u) ? ~u : (u | 0x80000000u);
}
// inverse of mapu
__device__ __forceinline__ float unmapu(unsigned x) {
  return __uint_as_float((x & 0x80000000u) ? (x & 0x7FFFFFFFu) : ~x);
}

union H4 { _Float16 h[4]; uint2 u2; };   // 4 packed fp16 <-> 8B

// ---- VALIDATED 256-thread GEMM body (r10-r15): 64x64 tile, 4x4 micro,
// double-buffered register staging. (Refuted alternatives: 512-thread body
// r12 [LDS-ratio], mega-fusion r14 [occupancy], +8KB LDS collect r16
// [occupancy], split-K atomics r17 [atomic epilogue cost].)
__device__ __forceinline__ void gemm_nt_body(const float* __restrict__ A,
                                             const float* __restrict__ B,
                                             float* __restrict__ C,
                                             int K, int N, int m0, int n0,
                                             float (*As)[68], float (*Bs)[68]) {
  const int t  = threadIdx.x;
  const int tx = t & 15, ty = t >> 4;
  const int rr = t >> 3, cc = (t & 7) << 2;
  float acc[4][4] = {};

  float4 fa0 = *(const float4*)&A[(size_t)(m0 + rr)      * K + cc];
  float4 fa1 = *(const float4*)&A[(size_t)(m0 + rr + 32) * K + cc];
  float4 fb0 = *(const float4*)&B[(size_t)(n0 + rr)      * K + cc];
  float4 fb1 = *(const float4*)&B[(size_t)(n0 + rr + 32) * K + cc];

  for (int k0 = 0; k0 < K; k0 += 32) {
    __syncthreads();
    As[cc + 0][rr] = fa0.x; As[cc + 1][rr] = fa0.y; As[cc + 2][rr] = fa0.z; As[cc + 3][rr] = fa0.w;
    As[cc + 0][rr + 32] = fa1.x; As[cc + 1][rr + 32] = fa1.y; As[cc + 2][rr + 32] = fa1.z; As[cc + 3][rr + 32] = fa1.w;
    Bs[cc + 0][rr] = fb0.x; Bs[cc + 1][rr] = fb0.y; Bs[cc + 2][rr] = fb0.z; Bs[cc + 3][rr] = fb0.w;
    Bs[cc + 0][rr + 32] = fb1.x; Bs[cc + 1][rr + 32] = fb1.y; Bs[cc + 2][rr + 32] = fb1.z; Bs[cc + 3][rr + 32] = fb1.w;
    __syncthreads();
    if (k0 + 32 < K) {
      fa0 = *(const float4*)&A[(size_t)(m0 + rr)      * K + k0 + 32 + cc];
      fa1 = *(const float4*)&A[(size_t)(m0 + rr + 32) * K + k0 + 32 + cc];
      fb0 = *(const float4*)&B[(size_t)(n0 + rr)      * K + k0 + 32 + cc];
      fb1 = *(const float4*)&B[(size_t)(n0 + rr + 32) * K + k0 + 32 + cc];
    }
#pragma unroll
    for (int kk = 0; kk < 32; ++kk) {
      const float4 a4 = *(const float4*)&As[kk][ty * 4];
      const float4 b4 = *(const float4*)&Bs[kk][tx * 4];
      const float a[4] = {a4.x, a4.y, a4.z, a4.w};
      const float b[4] = {b4.x, b4.y, b4.z, b4.w};
#pragma unroll
      for (int i = 0; i < 4; ++i)
#pragma unroll
        for (int j = 0; j < 4; ++j) acc[i][j] += a[i] * b[j];
    }
  }
#pragma unroll
  for (int i = 0; i < 4; ++i) {
    float4 o = make_float4(acc[i][0], acc[i][1], acc[i][2], acc[i][3]);
    *(float4*)&C[(size_t)(m0 + ty * 4 + i) * N + n0 + tx * 4] = o;
  }
}

__global__ __launch_bounds__(256) void gemm_nt(const float* __restrict__ A,
                                               const float* __restrict__ B,
                                               float* __restrict__ C,
                                               int M, int N, int K) {
  __shared__ float As[32][68];
  __shared__ float Bs[32][68];
  gemm_nt_body(A, B, C, K, N, blockIdx.x * 64, blockIdx.y * 64, As, Bs);
}

// Batched Q/K/V projection (768 blocks -> 3 blocks/CU; validated r10).
__global__ __launch_bounds__(256) void gemm_qkv(const float* __restrict__ x,
                                                const float* __restrict__ wq,
                                                const float* __restrict__ wk,
                                                const float* __restrict__ wv,
                                                float* __restrict__ Qb,
                                                float* __restrict__ Kb,
                                                float* __restrict__ Vb) {
  __shared__ float As[32][68];
  __shared__ float Bs[32][68];
  const int z = blockIdx.z;
  const float* B = (z == 0) ? wq : (z == 1) ? wk : wv;
  float*       C = (z == 0) ? Qb : (z == 1) ? Kb : Vb;
  gemm_nt_body(x, B, C, HIDDEN, HIDDEN, blockIdx.x * 64, blockIdx.y * 64, As, Bs);
}

// Fused importance+score GEMM. Tile 128q x 64k, depth 64. (validated)
__global__ __launch_bounds__(256) void score_gemm(const float* __restrict__ Q,
                                                  const float* __restrict__ K,
                                                  unsigned* __restrict__ impu,
                                                  _Float16* __restrict__ sch) {
  __shared__ float Qs[64][132];
  __shared__ float Ks[64][68];
  const int bid  = blockIdx.x;
  const int h    = bid & (NHEAD - 1);
  const int tile = bid >> 3;
  const int q0   = (tile & 15) * 128;
  const int k0   = (tile >> 4) * 64;
  const int t  = threadIdx.x;
  const int tx = t & 15, ty = t >> 4;

#pragma unroll
  for (int s = 0; s < 8; ++s) {
    const int sf = s * 256 + t;
    const int r = sf >> 4, c = (sf & 15) * 4;
    const float4 f = *(const float4*)&Q[(size_t)(q0 + r) * HIDDEN + h * DHEAD + c];
    Qs[c + 0][r] = f.x; Qs[c + 1][r] = f.y; Qs[c + 2][r] = f.z; Qs[c + 3][r] = f.w;
  }
#pragma unroll
  for (int s = 0; s < 4; ++s) {
    const int sf = s * 256 + t;
    const int r = sf >> 4, c = (sf & 15) * 4;
    const float4 f = *(const float4*)&K[(size_t)(k0 + r) * HIDDEN + h * DHEAD + c];
    Ks[c + 0][r] = f.x; Ks[c + 1][r] = f.y; Ks[c + 2][r] = f.z; Ks[c + 3][r] = f.w;
  }
  __syncthreads();

  float acc[8][4] = {};
#pragma unroll
  for (int d = 0; d < 32; ++d) {
    const float4 aa = *(const float4*)&Qs[d][ty * 8];
    const float4 ab = *(const float4*)&Qs[d][ty * 8 + 4];
    const float4 b4 = *(const float4*)&Ks[d][tx * 4];
    const float a[8] = {aa.x, aa.y, aa.z, aa.w, ab.x, ab.y, ab.z, ab.w};
    const float b[4] = {b4.x, b4.y, b4.z, b4.w};
#pragma unroll
    for (int i = 0; i < 8; ++i)
#pragma unroll
      for (int j = 0; j < 4; ++j) acc[i][j] += a[i] * b[j];
  }
  float simp[8][4];
#pragma unroll
  for (int i = 0; i < 8; ++i)
#pragma unroll
    for (int j = 0; j < 4; ++j) simp[i][j] = acc[i][j];
#pragma unroll
  for (int d = 32; d < 64; ++d) {
    const float4 aa = *(const float4*)&Qs[d][ty * 8];
    const float4 ab = *(const float4*)&Qs[d][ty * 8 + 4];
    const float4 b4 = *(const float4*)&Ks[d][tx * 4];
    const float a[8] = {aa.x, aa.y, aa.z, aa.w, ab.x, ab.y, ab.z, ab.w};
    const float b[4] = {b4.x, b4.y, b4.z, b4.w};
#pragma unroll
    for (int i = 0; i < 8; ++i)
#pragma unroll
      for (int j = 0; j < 4; ++j) acc[i][j] += a[i] * b[j];
  }

#pragma unroll
  for (int i = 0; i < 8; ++i) {
    const size_t gr = (size_t)(h * S_LEN) + q0 + ty * 8 + i;
    const size_t off = gr * S_LEN + k0 + tx * 4;
    *(uint4*)&impu[off] = make_uint4(mapu(simp[i][0]), mapu(simp[i][1]),
                                     mapu(simp[i][2]), mapu(simp[i][3]));
    H4 pk;
#pragma unroll
    for (int j = 0; j < 4; ++j) pk.h[j] = (_Float16)(acc[i][j] * SCALE_);
    *(uint2*)&sch[off] = pk.u2;
  }
}

// One wave per row. Two-level uniform value-bin select with cached packed
// bins + ballot collect (VALIDATED r13/r15: 86us, 26112 LDS, Occ 37%).
__global__ __launch_bounds__(512) void fused_select_pv(const unsigned* __restrict__ impu,
                                                       const _Float16* __restrict__ sch,
                                                       const float* __restrict__ V,
                                                       float* __restrict__ AO) {
  __shared__ unsigned hist[ROWS_A][256];           // 8 KB
  __shared__ float    sbuf[ROWS_A][NSEL];          // 8 KB (scratch: uint ebuf during select)
  __shared__ unsigned ibuf[ROWS_A][NSEL];          // 8 KB (element offsets idx<<9)
  __shared__ unsigned short eqbuf[ROWS_A][64];     // 1 KB
  __shared__ unsigned rstate[ROWS_A][2];

  const int t = threadIdx.x, wv = t >> 6, lane = t & 63;
  const unsigned long long lmask = (1ull << lane) - 1ull;
  const size_t gr = (size_t)blockIdx.x * ROWS_A + wv;   // gr = h*S + q
  const unsigned* rowp  = impu + gr * S_LEN;
  const _Float16* shrow = sch  + gr * S_LEN;

  uint4 u[8];
  H4    s4[8];
#pragma unroll
  for (int j = 0; j < 8; ++j) {
    u[j]     = *(const uint4*)&rowp[j * 256 + lane * 4];
    s4[j].u2 = *(const uint2*)&shrow[j * 256 + lane * 4];
  }
  // element idx for component e of u[j]: j*256 + lane*4 + e

  // ---- wave min/max in mapped domain ----
  unsigned um = u[0].x, uM = u[0].x;
#pragma unroll
  for (int j = 0; j < 8; ++j) {
    um = min(um, min(min(u[j].x, u[j].y), min(u[j].z, u[j].w)));
    uM = max(uM, max(max(u[j].x, u[j].y), max(u[j].z, u[j].w)));
  }
#pragma unroll
  for (int off = 32; off; off >>= 1) {
    um = min(um, (unsigned)__shfl_xor((int)um, off));
    uM = max(uM, (unsigned)__shfl_xor((int)uM, off));
  }

  unsigned bn[8];   // packed level-1 bins: 4 x u8 per u32 (computed once)
  unsigned T;
  if (uM == um) {
    T = uM;                                   // degenerate: all values equal
  } else {
    const float vmin  = unmapu(um);
    const float scale = 255.0f / (unmapu(uM) - vmin);

    // ---- level-1 histogram over uniform value bins (bins cached) ----
    *(uint4*)&hist[wv][lane * 4] = make_uint4(0u, 0u, 0u, 0u);
    WAVE_SYNC();
#pragma unroll
    for (int j = 0; j < 8; ++j) {
      const unsigned uu[4] = {u[j].x, u[j].y, u[j].z, u[j].w};
      unsigned pk = 0;
#pragma unroll
      for (int e = 0; e < 4; ++e) {
        int bb = (int)((unmapu(uu[e]) - vmin) * scale);
        bb = bb < 0 ? 0 : (bb > 255 ? 255 : bb);
        pk |= (unsigned)bb << (8 * e);
        atomicAdd(&hist[wv][bb], 1u);
      }
      bn[j] = pk;
    }
    WAVE_SYNC();
    // ---- suffix scan (descending bins) ----
    {
      const int g = 63 - lane;
      const uint4 c4 = *(const uint4*)&hist[wv][4 * g];
      const unsigned c0 = c4.x, c1 = c4.y, c2 = c4.z, c3 = c4.w;
      const unsigned lsum = c0 + c1 + c2 + c3;
      unsigned incl = lsum;
#pragma unroll
      for (int off = 1; off < 64; off <<= 1) {
        unsigned o = __shfl_up(incl, off);
        if (lane >= off) incl += o;
      }
      const unsigned excl = incl - lsum;
      const unsigned ab3 = excl, ab2 = excl + c3, ab1 = excl + c3 + c2, ab0 = excl + c3 + c2 + c1;
      if (ab3 < NSEL && NSEL <= ab3 + c3) { rstate[wv][0] = 4u*g+3u; rstate[wv][1] = NSEL - ab3; }
      if (ab2 < NSEL && NSEL <= ab2 + c2) { rstate[wv][0] = 4u*g+2u; rstate[wv][1] = NSEL - ab2; }
      if (ab1 < NSEL && NSEL <= ab1 + c1) { rstate[wv][0] = 4u*g+1u; rstate[wv][1] = NSEL - ab1; }
      if (ab0 < NSEL && NSEL <= ab0 + c0) { rstate[wv][0] = 4u*g+0u; rstate[wv][1] = NSEL - ab0; }
    }
    WAVE_SYNC();
    const unsigned B    = rstate[wv][0];
    const unsigned krem = rstate[wv][1];
    const unsigned nb   = hist[wv][B];

    if (nb <= 64) {
      // ---- collect bin-B values via cached bins (ballot-prefix) ----
      unsigned* ebufu = (unsigned*)&sbuf[wv][0];
      unsigned nbase = 0;
#pragma unroll
      for (int j = 0; j < 8; ++j) {
        const unsigned uu[4] = {u[j].x, u[j].y, u[j].z, u[j].w};
#pragma unroll
        for (int e = 0; e < 4; ++e) {
          const bool inb = (((bn[j] >> (8 * e)) & 0xFFu) == B);
          const unsigned long long m = __ballot(inb);
          if (inb) ebufu[nbase + (unsigned)__popcll(m & lmask)] = uu[e];
          nbase += (unsigned)__popcll(m);
        }
      }
      WAVE_SYNC();
      // ---- exact rank-select among nb (<=64) candidates ----
      const unsigned myv = (lane < (int)nb) ? ebufu[lane] : 0u;
      unsigned gtc = 0, eqc = 0;
      for (unsigned jj = 0; jj < nb; ++jj) {
        const unsigned bv = (unsigned)__shfl((int)myv, (int)jj);
        gtc += (bv > myv) ? 1u : 0u;
        eqc += (bv == myv) ? 1u : 0u;
      }
      if (lane < (int)nb && gtc < krem && krem <= gtc + eqc) rstate[wv][0] = myv;
      WAVE_SYNC();
      T = rstate[wv][0];
    } else {
      // ---- level 2 (rare): refine within bin B, global re-reads only ----
      unsigned m2min = 0xFFFFFFFFu, m2max = 0u;
      for (int i = lane; i < S_LEN; i += 64) {
        const unsigned x = rowp[i];
        int bb = (int)((unmapu(x) - vmin) * scale);
        bb = bb < 0 ? 0 : (bb > 255 ? 255 : bb);
        if (bb == (int)B) { m2min = min(m2min, x); m2max = max(m2max, x); }
      }
#pragma unroll
      for (int off = 32; off; off >>= 1) {
        m2min = min(m2min, (unsigned)__shfl_xor((int)m2min, off));
        m2max = max(m2max, (unsigned)__shfl_xor((int)m2max, off));
      }
      if (m2max == m2min) {
        T = m2max;
      } else {
        const float vlo2   = unmapu(m2min);
        const float scale2 = 255.0f / (unmapu(m2max) - vlo2);
        *(uint4*)&hist[wv][lane * 4] = make_uint4(0u, 0u, 0u, 0u);
        WAVE_SYNC();
        for (int i = lane; i < S_LEN; i += 64) {
          const unsigned x = rowp[i];
          const float v = unmapu(x);
          int bb = (int)((v - vmin) * scale);
          bb = bb < 0 ? 0 : (bb > 255 ? 255 : bb);
          if (bb == (int)B) {
            int b2 = (int)((v - vlo2) * scale2);
            b2 = b2 < 0 ? 0 : (b2 > 255 ? 255 : b2);
            atomicAdd(&hist[wv][b2], 1u);
          }
        }
        WAVE_SYNC();
        {
          const int g = 63 - lane;
          const uint4 c4 = *(const uint4*)&hist[wv][4 * g];
          const unsigned c0 = c4.x, c1 = c4.y, c2 = c4.z, c3 = c4.w;
          const unsigned lsum = c0 + c1 + c2 + c3;
          unsigned incl = lsum;
#pragma unroll
          for (int off = 1; off < 64; off <<= 1) {
            unsigned o = __shfl_up(incl, off);
            if (lane >= off) incl += o;
          }
          const unsigned excl = incl - lsum;
          const unsigned ab3 = excl, ab2 = excl + c3, ab1 = excl + c3 + c2, ab0 = excl + c3 + c2 + c1;
          if (ab3 < krem && krem <= ab3 + c3) { rstate[wv][0] = 4u*g+3u; rstate[wv][1] = krem - ab3; }
          if (ab2 < krem && krem <= ab2 + c2) { rstate[wv][0] = 4u*g+2u; rstate[wv][1] = krem - ab2; }
          if (ab1 < krem && krem <= ab1 + c1) { rstate[wv][0] = 4u*g+1u; rstate[wv][1] = krem - ab1; }
          if (ab0 < krem && krem <= ab0 + c0) { rstate[wv][0] = 4u*g+0u; rstate[wv][1] = krem - ab0; }
        }
        WAVE_SYNC();
        const unsigned B2    = rstate[wv][0];
        const unsigned krem2 = rstate[wv][1];
        const unsigned nb2   = hist[wv][B2];
        if (nb2 <= 64) {
          unsigned* ebufu = (unsigned*)&sbuf[wv][0];
          unsigned nbase = 0;
          for (int i = lane; i < S_LEN; i += 64) {
            const unsigned x = rowp[i];
            const float v = unmapu(x);
            int bb = (int)((v - vmin) * scale);
            bb = bb < 0 ? 0 : (bb > 255 ? 255 : bb);
            bool inb = false;
            if (bb == (int)B) {
              int b2 = (int)((v - vlo2) * scale2);
              b2 = b2 < 0 ? 0 : (b2 > 255 ? 255 : b2);
              inb = (b2 == (int)B2);
            }
            const unsigned long long m = __ballot(inb);
            if (inb) ebufu[nbase + (unsigned)__popcll(m & lmask)] = x;
            nbase += (unsigned)__popcll(m);
          }
          WAVE_SYNC();
          const unsigned myv = (lane < (int)nb2) ? ebufu[lane] : 0u;
          unsigned gtc = 0, eqc = 0;
          for (unsigned jj = 0; jj < nb2; ++jj) {
            const unsigned bv = (unsigned)__shfl((int)myv, (int)jj);
            gtc += (bv > myv) ? 1u : 0u;
            eqc += (bv == myv) ? 1u : 0u;
          }
          if (lane < (int)nb2 && gtc < krem2 && krem2 <= gtc + eqc) rstate[wv][0] = myv;
          WAVE_SYNC();
          T = rstate[wv][0];
        } else {
          // ---- ultimate safety: lane-0 serial exact byte radix ----
          if (lane == 0) {
            unsigned pfx = 0, kr = NSEL;
            for (int rb = 3; rb >= 0; --rb) {
              for (int i2 = 0; i2 < 256; ++i2) hist[wv][i2] = 0u;
              for (int i2 = 0; i2 < S_LEN; ++i2) {
                const unsigned x = rowp[i2];
                if (rb == 3 || ((x >> (rb * 8 + 8)) == pfx)) hist[wv][(x >> (rb * 8)) & 0xFF]++;
              }
              unsigned cum = 0, sel = 0;
              for (int bb2 = 255; bb2 >= 0; --bb2) {
                if (kr <= cum + hist[wv][bb2]) { sel = (unsigned)bb2; kr -= cum; break; }
                cum += hist[wv][bb2];
              }
              pfx = (pfx << 8) | sel;
            }
            rstate[wv][0] = pfx;
          }
          WAVE_SYNC();
          T = rstate[wv][0];
        }
      }
    }
  }

  // ---- collect (offset, score): ballot-prefix (validated form) ----
  unsigned base_gt = 0, base_eq = 0;
#pragma unroll
  for (int j = 0; j < 8; ++j) {
    const unsigned uu[4] = {u[j].x, u[j].y, u[j].z, u[j].w};
#pragma unroll
    for (int e = 0; e < 4; ++e) {
      const unsigned v = uu[e];
      const int i = j * 256 + lane * 4 + e;
      const bool gt = (v > T), eq = (v == T);
      const unsigned long long mg = __ballot(gt);
      const unsigned long long me = __ballot(eq);
      if (gt) {
        const unsigned p = base_gt + (unsigned)__popcll(mg & lmask);
        ibuf[wv][p] = (unsigned)i << 9;       // element offset idx*HIDDEN
        sbuf[wv][p] = (float)s4[j].h[e];
      }
      if (eq) {
        const unsigned p = base_eq + (unsigned)__popcll(me & lmask);
        if (p < 64) eqbuf[wv][p] = (unsigned short)i;   // index-ascending
      }
      base_gt += (unsigned)__popcll(mg);
      base_eq += (unsigned)__popcll(me);
    }
  }
  WAVE_SYNC();
  const unsigned ngt = base_gt, ne = base_eq;
  const unsigned need = NSEL - ngt;
  if (ne == need && ne <= 64) {               // all ties taken: order irrelevant
    for (unsigned j = lane; j < ne; j += 64) {
      const unsigned short ix = eqbuf[wv][j];
      ibuf[wv][ngt + j] = (unsigned)ix << 9;
      sbuf[wv][ngt + j] = (float)shrow[ix];
    }
  } else if (lane == 0) {
    if (ne <= 64) {                           // ties ascending: take lowest `need`
      for (unsigned j = 0; j < need; ++j) {
        const unsigned short ix = eqbuf[wv][j];
        ibuf[wv][ngt + j] = (unsigned)ix << 9;
        sbuf[wv][ngt + j] = (float)shrow[ix];
      }
    } else {                                  // pathological: serial ascending scan
      unsigned taken = 0;
      for (int i = 0; i < S_LEN && taken < need; ++i)
        if (rowp[i] == T) { ibuf[wv][ngt + taken] = (unsigned)i << 9; sbuf[wv][ngt + taken] = (float)shrow[i]; ++taken; }
    }
  }
  WAVE_SYNC();

  // ---- softmax over the 256 selected scores ----
  float sc[4];
#pragma unroll
  for (int m = 0; m < 4; ++m) sc[m] = sbuf[wv][lane * 4 + m];
  float mx = fmaxf(fmaxf(sc[0], sc[1]), fmaxf(sc[2], sc[3]));
#pragma unroll
  for (int off = 32; off; off >>= 1) mx = fmaxf(mx, __shfl_xor(mx, off));
  float zs = 0.f;
#pragma unroll
  for (int m = 0; m < 4; ++m) { sc[m] = expf(sc[m] - mx); zs += sc[m]; }
#pragma unroll
  for (int off = 32; off; off >>= 1) zs += __shfl_xor(zs, off);
  const float rz = 1.0f / zs;
  *(float4*)&sbuf[wv][lane * 4] = make_float4(sc[0], sc[1], sc[2], sc[3]);
  WAVE_SYNC();

  // ---- PV: wave-contiguous 256B V-row reads; offsets precomputed ----
  const int h = (int)(gr >> 11), q = (int)(gr & (S_LEN - 1));
  const float* Vhl = V + h * DHEAD + lane;
  float outv = 0.f;
#pragma unroll 8
  for (int j = 0; j < NSEL; j += 4) {
    const uint4  id4 = *(const uint4*)&ibuf[wv][j];
    const float4 w4  = *(const float4*)&sbuf[wv][j];
    outv += w4.x * Vhl[id4.x];
    outv += w4.y * Vhl[id4.y];
    outv += w4.z * Vhl[id4.z];
    outv += w4.w * Vhl[id4.w];
  }
  AO[(size_t)q * HIDDEN + h * DHEAD + lane] = outv * rz;
}

extern "C" void kernel_launch(void* const* d_in, const int* in_sizes, int n_in,
                              void* d_out, int out_size, void* d_ws, size_t ws_size,
                              hipStream_t stream) {
  const float* x  = (const float*)d_in[0];
  const float* wq = (const float*)d_in[1];
  const float* wk = (const float*)d_in[2];
  const float* wv = (const float*)d_in[3];
  const float* wo = (const float*)d_in[4];
  float* out = (float*)d_out;

  float* Qb = (float*)d_ws;
  float* Kb = Qb + (size_t)S_LEN * HIDDEN;
  float* Vb = Kb + (size_t)S_LEN * HIDDEN;
  float* AO = Vb + (size_t)S_LEN * HIDDEN;
  void*  tail = (void*)(AO + (size_t)S_LEN * HIDDEN);

  const size_t elems = (size_t)NHEAD * S_LEN * S_LEN;
  unsigned* impu = (unsigned*)tail;
  _Float16* sch  = (_Float16*)(impu + elems);

  dim3 g(S_LEN / 64, HIDDEN / 64);
  gemm_qkv<<<dim3(S_LEN / 64, HIDDEN / 64, 3), 256, 0, stream>>>(x, wq, wk, wv, Qb, Kb, Vb);
  score_gemm<<<dim3(NHEAD * 16 * 32), 256, 0, stream>>>(Qb, Kb, impu, sch);
  fused_select_pv<<<dim3(NHEAD * S_LEN / ROWS_A), 512, 0, stream>>>(impu, sch, Vb, AO);
  gemm_nt<<<g, 256, 0, stream>>>(AO, wo, out, S_LEN, HIDDEN, HIDDEN);
}